// Round 6
// baseline (331.181 us; speedup 1.0000x reference)
//
#include <hip/hip_runtime.h>
#include <hip/hip_cooperative_groups.h>

namespace cg = cooperative_groups;

constexpr int CH = 128;
constexpr int HH = 48, WW = 48;
constexpr int PP = HH * WW;        // 2304
constexpr int NPIX = 2 * PP;       // 4608
constexpr int K2 = 169;            // 13x13 window
constexpr int GRID = 1152;         // NPIX/4: 4 px per block, 1 px per wave

// workspace layout (in floats)
constexpr size_t OFF_XT  = 0;                              // [NPIX][CH] pixel-major x
constexpr size_t OFF_RN  = OFF_XT + (size_t)NPIX * CH;     // [NPIX] 1/max(||x||,eps)
constexpr size_t OFF_DF  = OFF_RN + NPIX;                  // [NPIX] df
constexpr size_t OFF_MM  = OFF_DF + NPIX;                  // [4] uint min/max per batch
constexpr size_t OFF_GN  = OFF_MM + 4;                     // [64*2] mu,rstd
constexpr size_t OFF_GNP = OFF_GN + 128;                   // [288 units][16] GN partials
constexpr size_t OFF_W1T = OFF_GNP + 288 * 16;             // [32][256][4] packed w1^T
constexpr size_t OFF_W2T = OFF_W1T + 32768;                // [64][128][4] packed w2^T
constexpr size_t WS_FLOATS = OFF_W2T + 32768;

__device__ __forceinline__ int refl(int t) {
    return t < 0 ? -t : (t > 47 ? 94 - t : t);
}

union SMem {
    struct { float t[32][65]; } p0;                       // 8320 B (max)
    struct { float dfl[4]; } p1;
    struct { float sims[4][176]; } p2a;                   // 2816 B
    struct { float elds[4][128]; float hlds[4][256]; } p2b;  // 6144 B
};

// ===== phase 0: transpose x -> xt, GN partials, weight packing, mm init ====
__device__ __forceinline__ void phase0(SMem& sm,
                                       const float* __restrict__ x,
                                       const float* __restrict__ w1,
                                       const float* __restrict__ w2,
                                       float* __restrict__ xt,
                                       float* __restrict__ gnp,
                                       float* __restrict__ w1t,
                                       float* __restrict__ w2t,
                                       unsigned* __restrict__ mm) {
    const int tid = threadIdx.x;
    // units: 72 tiles (64 px) x 4 chunks (32 ch)
    for (int u = blockIdx.x; u < 288; u += gridDim.x) {
        const int tile = u >> 2, q = u & 3;
        const int p0 = tile * 64;                // 36 tiles per batch, no straddle
        const int b = p0 / PP, pb = p0 % PP;
        const int pl = tid & 63, cb = tid >> 6;
        const float* xb = x + (size_t)b * CH * PP + (size_t)(q * 32) * PP + pb;
#pragma unroll
        for (int r = 0; r < 8; r++) {
            int c = r * 4 + cb;
            sm.p0.t[c][pl] = xb[(size_t)c * PP + pl];
        }
        __syncthreads();
        {
            const int c4 = tid & 7, pq = tid >> 3;
#pragma unroll
            for (int r = 0; r < 2; r++) {
                int px = r * 32 + pq;
                float4 v = make_float4(sm.p0.t[c4 * 4][px], sm.p0.t[c4 * 4 + 1][px],
                                       sm.p0.t[c4 * 4 + 2][px], sm.p0.t[c4 * 4 + 3][px]);
                ((float4*)(xt + (size_t)(p0 + px) * CH + q * 32))[c4] = v;
            }
        }
        {   // GN partials: local group j (global g = q*8+j); 32 lanes x (2px * 4ch)
            const int j = tid >> 5, part = tid & 31;
            float s = 0.f, sq = 0.f;
#pragma unroll
            for (int pi = 0; pi < 2; pi++) {
                int px = part * 2 + pi;
#pragma unroll
                for (int i = 0; i < 4; i++) {
                    float v = sm.p0.t[j * 4 + i][px];
                    s += v; sq += v * v;
                }
            }
#pragma unroll
            for (int m = 16; m; m >>= 1) { s += __shfl_xor(s, m); sq += __shfl_xor(sq, m); }
            if (part == 0) { gnp[u * 16 + j * 2] = s; gnp[u * 16 + j * 2 + 1] = sq; }
        }
        __syncthreads();
    }
    // pack w1 -> w1t4[c4*256+o], w2 -> w2t4[o4*128+c] (reads coalesced)
    for (int base = blockIdx.x * 256; base < 2 * 32768; base += gridDim.x * 256) {
        int idx = base + tid;
        if (idx < 32768) {                       // w1[o][c], o=idx>>7, c=idx&127
            int o = idx >> 7, c = idx & 127;
            int c4 = c >> 2, i = c & 3;
            w1t[(size_t)(c4 * 256 + o) * 4 + i] = w1[idx];
        } else {                                 // w2[c][oo], c=i2>>8, oo=i2&255
            int i2 = idx - 32768;
            int c = i2 >> 8, oo = i2 & 255;
            int o4 = oo >> 2, i = oo & 3;
            w2t[(size_t)(o4 * 128 + c) * 4 + i] = w2[i2];
        }
    }
    if (blockIdx.x == 0 && tid < 4) mm[tid] = (tid & 1) ? 0u : 0x7f800000u;
}

// ===== phase 1: GN finalize (block 0), df/rn + per-batch min/max ==========
__device__ __forceinline__ void phase1(SMem& sm,
                                       const float* __restrict__ xt,
                                       const float* __restrict__ gnp,
                                       float* __restrict__ df,
                                       float* __restrict__ rn,
                                       unsigned* __restrict__ mm,
                                       float* __restrict__ gnb) {
    const int tid = threadIdx.x;
    if (blockIdx.x == 0 && tid < 64) {           // GN finalize: tid = b*32+g
        const int b = tid >> 5, g = tid & 31;
        const int q = g >> 3, j = g & 7;
        float s = 0.f, sq = 0.f;
#pragma unroll 4
        for (int t2 = 0; t2 < 36; t2++) {
            int u = (b * 36 + t2) * 4 + q;
            s += gnp[u * 16 + j * 2];
            sq += gnp[u * 16 + j * 2 + 1];
        }
        float mu = s / 9216.f;
        float var = sq / 9216.f - mu * mu;
        gnb[tid * 2] = mu;
        gnb[tid * 2 + 1] = 1.f / sqrtf(var + 1e-5f);
    }
    const int wv = tid >> 6, lane = tid & 63;
    for (int base = blockIdx.x * 4; base < NPIX; base += gridDim.x * 4) {
        const int pix = base + wv;               // 4 | PP: no batch straddle
        const int b = pix / PP, p = pix % PP;
        const int h = p / WW, w = p % WW;
        float py = 0.5f * h - 0.25f; int y0 = (int)floorf(py); float fy = py - (float)y0;
        float px = 0.5f * w - 0.25f; int x0 = (int)floorf(px); float fx = px - (float)x0;
        int y0c = max(y0, 0), y1c = min(y0 + 1, 23);
        int x0c = max(x0, 0), x1c = min(x0 + 1, 23);
        float w00 = (1.f - fy) * (1.f - fx), w01 = (1.f - fy) * fx;
        float w10 = fy * (1.f - fx), w11 = fy * fx;
        auto ld2 = [&](int yy, int xx) {
            return ((const float2*)(xt + ((size_t)(b * PP + yy * WW + xx)) * CH))[lane];
        };
        auto xd = [&](int yc, int xc) {          // 2x2 avg of full-res (exact down)
            float2 a = ld2(2 * yc, 2 * xc), bq = ld2(2 * yc, 2 * xc + 1);
            float2 c = ld2(2 * yc + 1, 2 * xc), d = ld2(2 * yc + 1, 2 * xc + 1);
            return make_float2(0.25f * (a.x + bq.x + c.x + d.x),
                               0.25f * (a.y + bq.y + c.y + d.y));
        };
        float2 v00 = xd(y0c, x0c), v01 = xd(y0c, x1c);
        float2 v10 = xd(y1c, x0c), v11 = xd(y1c, x1c);
        float2 xv = ((const float2*)(xt + (size_t)pix * CH))[lane];
        float ux = w00 * v00.x + w01 * v01.x + w10 * v10.x + w11 * v11.x;
        float uy = w00 * v00.y + w01 * v01.y + w10 * v10.y + w11 * v11.y;
        float ds = fabsf(xv.x - ux) + fabsf(xv.y - uy);
        float ss = xv.x * xv.x + xv.y * xv.y;
#pragma unroll
        for (int s = 32; s; s >>= 1) { ds += __shfl_xor(ds, s); ss += __shfl_xor(ss, s); }
        if (lane == 0) {
            df[pix] = ds;
            rn[pix] = 1.f / fmaxf(sqrtf(ss), 1e-12f);
            sm.p1.dfl[wv] = ds;
        }
        __syncthreads();
        if (tid == 0) {
            float mn = fminf(fminf(sm.p1.dfl[0], sm.p1.dfl[1]),
                             fminf(sm.p1.dfl[2], sm.p1.dfl[3]));
            float mx = fmaxf(fmaxf(sm.p1.dfl[0], sm.p1.dfl[1]),
                             fmaxf(sm.p1.dfl[2], sm.p1.dfl[3]));
            atomicMin(&mm[b * 2], __float_as_uint(mn));
            atomicMax(&mm[b * 2 + 1], __float_as_uint(mx));
        }
        __syncthreads();
    }
}

// ===== phase 2: IPG core (1 px/wave, zero-barrier sims) + GN + fused FFN ==
__device__ __forceinline__ void phase2(SMem& sm,
                                       const float* __restrict__ xt,
                                       const float* __restrict__ rn,
                                       const float* __restrict__ df,
                                       const unsigned* __restrict__ mm,
                                       const float* __restrict__ gnb,
                                       const float* __restrict__ gamma,
                                       const float* __restrict__ beta,
                                       const float* __restrict__ w1t,
                                       const float* __restrict__ w2t,
                                       const float* __restrict__ b1f,
                                       const float* __restrict__ b2f,
                                       float* __restrict__ out) {
    const int tid = threadIdx.x, wv = tid >> 6, lane = tid & 63;
    for (int base = blockIdx.x * 4; base < NPIX; base += gridDim.x * 4) {
        const int pix = base + wv;
        const int b = pix / PP, p = pix % PP;
        const int h = p / WW, w = p % WW;
        const int bb = b * PP;
        const int g8 = lane >> 3, cl = lane & 7;

        float4 ctr[4];
        const float4* cp = (const float4*)(xt + (size_t)pix * CH) + cl;
#pragma unroll
        for (int c = 0; c < 4; c++) ctr[c] = cp[c * 8];
        const float rnp = rn[pix];

        // sims: 22 batches x 8 offsets; group g8 = offset, cl = 4-ch slice
        for (int kb = 0; kb < 176; kb += 8) {
            const int k = kb + g8;
            const int krow = k / 13, kcol = k - krow * 13;
            const int yy = refl(h + krow - 6), xx = refl(w + kcol - 6);
            const int p2 = bb + yy * WW + xx;
            const float4* rp = (const float4*)(xt + (size_t)p2 * CH) + cl;
            float dot = 0.f;
#pragma unroll
            for (int c = 0; c < 4; c++) {
                float4 v = rp[c * 8];
                dot += v.x * ctr[c].x + v.y * ctr[c].y + v.z * ctr[c].z + v.w * ctr[c].w;
            }
            dot += __shfl_xor(dot, 1);
            dot += __shfl_xor(dot, 2);
            dot += __shfl_xor(dot, 4);
            float s = dot * rnp * rn[p2];
            if (cl == 0 && k < K2) sm.p2a.sims[wv][k] = s;
        }

        // top-cc extraction (value desc, index asc) + fused gather
        float s0 = sm.p2a.sims[wv][lane];
        float s1 = (64 + lane < K2) ? sm.p2a.sims[wv][64 + lane] : -1e30f;
        float s2 = (128 + lane < K2) ? sm.p2a.sims[wv][128 + lane] : -1e30f;
        const float dmin = __uint_as_float(mm[b * 2]);
        const float dmax = __uint_as_float(mm[b * 2 + 1]);
        const float dn = (df[pix] - dmin) / (dmax - dmin + 1e-8f);
        const int cc = 1 + (int)rintf(dn * 15.f);

        float wsum = 0.f, ax = 0.f, ay = 0.f;
        for (int i = 0; i < cc; ++i) {
            float gm = fmaxf(fmaxf(s0, s1), s2);
#pragma unroll
            for (int sft = 1; sft <= 32; sft <<= 1) gm = fmaxf(gm, __shfl_xor(gm, sft));
            unsigned long long m0 = __ballot(s0 == gm);
            unsigned long long m1 = __ballot(s1 == gm);
            unsigned long long m2 = __ballot(s2 == gm);
            int kw = m0 ? (__ffsll(m0) - 1)
                   : m1 ? (64 + __ffsll(m1) - 1)
                        : (128 + __ffsll(m2) - 1);
            bool me = (lane == (kw & 63));
            s0 = (me && kw < 64) ? -1e30f : s0;
            s1 = (me && kw >= 64 && kw < 128) ? -1e30f : s1;
            s2 = (me && kw >= 128) ? -1e30f : s2;
            float wt = expf(gm);
            wsum += wt;
            int krow = kw / 13, kcol = kw - krow * 13;
            int p2 = bb + refl(h + krow - 6) * WW + refl(w + kcol - 6);
            float2 v = ((const float2*)(xt + (size_t)p2 * CH))[lane];
            ax += wt * v.x; ay += wt * v.y;
        }
        const float invw = 1.f / wsum;

        // GroupNorm + residual -> enhanced (registers)
        float2 xv = ((const float2*)(xt + (size_t)pix * CH))[lane];
        const int c0 = lane * 2, grp = lane >> 1;
        const float mu = gnb[(b * 32 + grp) * 2], rstd = gnb[(b * 32 + grp) * 2 + 1];
        float e0 = ax * invw + (xv.x - mu) * rstd * gamma[c0] + beta[c0];
        float e1 = ay * invw + (xv.y - mu) * rstd * gamma[c0 + 1] + beta[c0 + 1];

        __syncthreads();                          // all waves done with sims
        ((float2*)sm.p2b.elds[wv])[lane] = make_float2(e0, e1);
        __syncthreads();

        // FFN stage 1: thread = output o; w1t4 coalesced, elds broadcast
        {
            float acc4[4] = {0.f, 0.f, 0.f, 0.f};
            const float4* wp = ((const float4*)w1t) + tid;
            for (int c4 = 0; c4 < 32; c4++) {
                float4 wv4 = wp[c4 * 256];
#pragma unroll
                for (int px = 0; px < 4; px++) {
                    float4 ev = *(const float4*)&sm.p2b.elds[px][c4 * 4];
                    acc4[px] += wv4.x * ev.x + wv4.y * ev.y + wv4.z * ev.z + wv4.w * ev.w;
                }
            }
            float bv = b1f[tid];
#pragma unroll
            for (int px = 0; px < 4; px++)
                sm.p2b.hlds[px][tid] = fmaxf(acc4[px] + bv, 0.f);
        }
        __syncthreads();
        // FFN stage 2 + residual: thread = (c, hf); w2t4 coalesced
        {
            const int c = tid & 127, hf = tid >> 7;
            const int px0 = hf * 2;
            float acc2[2] = {0.f, 0.f};
            const float4* wp2 = ((const float4*)w2t) + c;
            for (int o4 = 0; o4 < 64; o4++) {
                float4 wv4 = wp2[o4 * 128];
#pragma unroll
                for (int j = 0; j < 2; j++) {
                    float4 hv = *(const float4*)&sm.p2b.hlds[px0 + j][o4 * 4];
                    acc2[j] += wv4.x * hv.x + wv4.y * hv.y + wv4.z * hv.z + wv4.w * hv.w;
                }
            }
            float bv = b2f[c];
            float2 o2;
            o2.x = sm.p2b.elds[px0 + 0][c] + acc2[0] + bv;
            o2.y = sm.p2b.elds[px0 + 1][c] + acc2[1] + bv;
            *(float2*)(out + ((size_t)(b * CH + c)) * PP + (base % PP) + px0) = o2;
        }
        __syncthreads();
    }
}

// ===== kernels =============================================================
__global__ __launch_bounds__(256, 5) void k_fused(
        const float* __restrict__ x, const float* __restrict__ gamma,
        const float* __restrict__ beta, const float* __restrict__ w1,
        const float* __restrict__ b1, const float* __restrict__ w2,
        const float* __restrict__ b2, float* __restrict__ xt,
        float* __restrict__ rn, float* __restrict__ df,
        unsigned* __restrict__ mm, float* __restrict__ gnb,
        float* __restrict__ gnp, float* __restrict__ w1t,
        float* __restrict__ w2t, float* __restrict__ out) {
    __shared__ SMem sm;
    cg::grid_group grid = cg::this_grid();
    phase0(sm, x, w1, w2, xt, gnp, w1t, w2t, mm);
    grid.sync();
    phase1(sm, xt, gnp, df, rn, mm, gnb);
    grid.sync();
    phase2(sm, xt, rn, df, mm, gnb, gamma, beta, w1t, w2t, b1, b2, out);
}

// fallback (non-cooperative) versions of the same phases
__global__ __launch_bounds__(256, 5) void k_p0(
        const float* __restrict__ x, const float* __restrict__ w1,
        const float* __restrict__ w2, float* __restrict__ xt,
        float* __restrict__ gnp, float* __restrict__ w1t,
        float* __restrict__ w2t, unsigned* __restrict__ mm) {
    __shared__ SMem sm;
    phase0(sm, x, w1, w2, xt, gnp, w1t, w2t, mm);
}
__global__ __launch_bounds__(256, 5) void k_p1(
        const float* __restrict__ xt, const float* __restrict__ gnp,
        float* __restrict__ df, float* __restrict__ rn,
        unsigned* __restrict__ mm, float* __restrict__ gnb) {
    __shared__ SMem sm;
    phase1(sm, xt, gnp, df, rn, mm, gnb);
}
__global__ __launch_bounds__(256, 5) void k_p2(
        const float* __restrict__ xt, const float* __restrict__ rn,
        const float* __restrict__ df, const unsigned* __restrict__ mm,
        const float* __restrict__ gnb, const float* __restrict__ gamma,
        const float* __restrict__ beta, const float* __restrict__ w1t,
        const float* __restrict__ w2t, const float* __restrict__ b1,
        const float* __restrict__ b2, float* __restrict__ out) {
    __shared__ SMem sm;
    phase2(sm, xt, rn, df, mm, gnb, gamma, beta, w1t, w2t, b1, b2, out);
}

extern "C" void kernel_launch(void* const* d_in, const int* in_sizes, int n_in,
                              void* d_out, int out_size, void* d_ws, size_t ws_size,
                              hipStream_t stream) {
    (void)in_sizes; (void)n_in; (void)out_size;
    if (ws_size < WS_FLOATS * sizeof(float)) return;  // would corrupt; fail visibly

    const float* x     = (const float*)d_in[0];
    const float* gamma = (const float*)d_in[1];
    const float* beta  = (const float*)d_in[2];
    const float* w1    = (const float*)d_in[3];
    const float* b1    = (const float*)d_in[4];
    const float* w2    = (const float*)d_in[5];
    const float* b2    = (const float*)d_in[6];
    float* ws = (float*)d_ws;
    float* xt    = ws + OFF_XT;
    float* rn    = ws + OFF_RN;
    float* df    = ws + OFF_DF;
    unsigned* mm = (unsigned*)(ws + OFF_MM);
    float* gnb   = ws + OFF_GN;
    float* gnp   = ws + OFF_GNP;
    float* w1t   = ws + OFF_W1T;
    float* w2t   = ws + OFF_W2T;
    float* out   = (float*)d_out;

    void* args[] = { (void*)&x, (void*)&gamma, (void*)&beta, (void*)&w1, (void*)&b1,
                     (void*)&w2, (void*)&b2, (void*)&xt, (void*)&rn, (void*)&df,
                     (void*)&mm, (void*)&gnb, (void*)&gnp, (void*)&w1t, (void*)&w2t,
                     (void*)&out };
    hipError_t err = hipLaunchCooperativeKernel((const void*)k_fused, dim3(GRID),
                                                dim3(256), args, 0, stream);
    if (err != hipSuccess) {
        (void)hipGetLastError();  // clear; fall back to 3 plain launches
        hipLaunchKernelGGL(k_p0, dim3(GRID), dim3(256), 0, stream,
                           x, w1, w2, xt, gnp, w1t, w2t, mm);
        hipLaunchKernelGGL(k_p1, dim3(GRID), dim3(256), 0, stream,
                           xt, gnp, df, rn, mm, gnb);
        hipLaunchKernelGGL(k_p2, dim3(GRID), dim3(256), 0, stream,
                           xt, rn, df, mm, gnb, gamma, beta, w1t, w2t, b1, b2, out);
    }
}

// Round 7
// 63.886 us; speedup vs baseline: 5.1839x; 5.1839x over previous
//
#include <hip/hip_runtime.h>

constexpr int CH = 128;
constexpr int WW = 48;
constexpr int PP = 2304;           // 48*48
constexpr int NPIX = 4608;         // 2*PP
constexpr int K2 = 169;            // 13x13 window

// workspace layout (floats). Every cell is rewritten each call (no stale state).
constexpr size_t OFF_XT  = 0;                              // [NPIX][CH] pixel-major x
constexpr size_t OFF_RN  = OFF_XT + (size_t)NPIX * CH;     // [NPIX] 1/max(||x||,eps)
constexpr size_t OFF_DF  = OFF_RN + NPIX;                  // [NPIX] df
constexpr size_t OFF_GNP = OFF_DF + NPIX;                  // [288 units][16] GN partials
constexpr size_t OFF_MMP = OFF_GNP + 288 * 16;             // [72 strips][2] min/max partials
constexpr size_t OFF_W1T = OFF_MMP + 144;                  // [32][256][4] packed w1^T
constexpr size_t OFF_W2T = OFF_W1T + 32768;                // [64][128][4] packed w2^T
constexpr size_t WS_FLOATS = OFF_W2T + 32768;

__device__ __forceinline__ int refl(int t) {
    return t < 0 ? -t : (t > 47 ? 94 - t : t);
}

// ===== kernel A: transpose + GN partials | df/rn/minmax partials | pack ====
__global__ __launch_bounds__(256) void kA(const float* __restrict__ x,
                                          const float* __restrict__ w1,
                                          const float* __restrict__ w2,
                                          float* __restrict__ xt,
                                          float* __restrict__ gnp,
                                          float* __restrict__ w1t,
                                          float* __restrict__ w2t,
                                          float* __restrict__ df,
                                          float* __restrict__ rn,
                                          float* __restrict__ mmp) {
    __shared__ union { float t[32][65]; float red[4][64][2]; } sm;
    const int tid = threadIdx.x;
    const int bid = blockIdx.x;
    if (bid < 288) {
        // ---- transpose unit: 64 px x 32 ch; GN partials ----
        const int tile = bid >> 2, q = bid & 3;
        const int p0 = tile * 64;                 // 36 tiles/batch, no straddle
        const int b = p0 / PP, pb = p0 % PP;
        const int pl = tid & 63, cb = tid >> 6;
        const float* xb = x + (size_t)b * CH * PP + (size_t)(q * 32) * PP + pb;
#pragma unroll
        for (int r = 0; r < 8; r++) {
            int c = r * 4 + cb;
            sm.t[c][pl] = xb[(size_t)c * PP + pl];
        }
        __syncthreads();
        {
            const int c4 = tid & 7, pq = tid >> 3;
#pragma unroll
            for (int r = 0; r < 2; r++) {
                int px = r * 32 + pq;
                float4 v = make_float4(sm.t[c4 * 4][px], sm.t[c4 * 4 + 1][px],
                                       sm.t[c4 * 4 + 2][px], sm.t[c4 * 4 + 3][px]);
                ((float4*)(xt + (size_t)(p0 + px) * CH + q * 32))[c4] = v;
            }
        }
        {   // GN partials: local group j -> global g=q*8+j (4 consecutive ch)
            const int j = tid >> 5, part = tid & 31;
            float s = 0.f, sq = 0.f;
#pragma unroll
            for (int pi = 0; pi < 2; pi++) {
                int px = part * 2 + pi;
#pragma unroll
                for (int i = 0; i < 4; i++) {
                    float v = sm.t[j * 4 + i][px];
                    s += v; sq += v * v;
                }
            }
#pragma unroll
            for (int m = 16; m; m >>= 1) { s += __shfl_xor(s, m); sq += __shfl_xor(sq, m); }
            if (part == 0) { gnp[bid * 16 + j * 2] = s; gnp[bid * 16 + j * 2 + 1] = sq; }
        }
    } else if (bid < 360) {
        // ---- df strip: 64 px, from channel-major x; lane=pixel ----
        const int strip = bid - 288;
        const int p0 = strip * 64;                // 36 strips/batch
        const int b = p0 / PP;
        const int wv = tid >> 6, lane = tid & 63;
        const int p = (p0 % PP) + lane;
        const int h = p / WW, w = p % WW;
        float py = 0.5f * h - 0.25f; int y0 = (int)floorf(py); float fy = py - (float)y0;
        float px_ = 0.5f * w - 0.25f; int x0 = (int)floorf(px_); float fx = px_ - (float)x0;
        int y0c = max(y0, 0), y1c = min(y0 + 1, 23);
        int x0c = max(x0, 0), x1c = min(x0 + 1, 23);
        // up = q00*S(y0c,x0c)+q01*S(y0c,x1c)+q10*S(y1c,x0c)+q11*S(y1c,x1c),
        // S = sum of the 2x2 full-res quad (xd = 0.25*S folded into q).
        float q00 = 0.25f * (1.f - fy) * (1.f - fx), q01 = 0.25f * (1.f - fy) * fx;
        float q10 = 0.25f * fy * (1.f - fx),        q11 = 0.25f * fy * fx;
        int r0 = (2 * y0c) * WW, r1 = (2 * y0c + 1) * WW;
        int r2 = (2 * y1c) * WW, r3 = (2 * y1c + 1) * WW;
        int ca = 2 * x0c, cb2 = 2 * x1c;
        const float* xc = x + (size_t)b * CH * PP + (size_t)(wv * 32) * PP;
        float ds = 0.f, ss = 0.f;
        for (int c = 0; c < 32; c++) {
            const float* xp = xc + (size_t)c * PP;
            float xv = xp[p];
            float s00 = xp[r0 + ca] + xp[r0 + ca + 1] + xp[r1 + ca] + xp[r1 + ca + 1];
            float s01 = xp[r0 + cb2] + xp[r0 + cb2 + 1] + xp[r1 + cb2] + xp[r1 + cb2 + 1];
            float s10 = xp[r2 + ca] + xp[r2 + ca + 1] + xp[r3 + ca] + xp[r3 + ca + 1];
            float s11 = xp[r2 + cb2] + xp[r2 + cb2 + 1] + xp[r3 + cb2] + xp[r3 + cb2 + 1];
            float up = q00 * s00 + q01 * s01 + q10 * s10 + q11 * s11;
            ds += fabsf(xv - up);
            ss += xv * xv;
        }
        sm.red[wv][lane][0] = ds; sm.red[wv][lane][1] = ss;
        __syncthreads();
        if (wv == 0) {
            float dst = sm.red[0][lane][0] + sm.red[1][lane][0] +
                        sm.red[2][lane][0] + sm.red[3][lane][0];
            float sst = sm.red[0][lane][1] + sm.red[1][lane][1] +
                        sm.red[2][lane][1] + sm.red[3][lane][1];
            df[p0 + lane] = dst;
            rn[p0 + lane] = 1.f / fmaxf(sqrtf(sst), 1e-12f);
            float mn = dst, mx = dst;
#pragma unroll
            for (int m = 32; m; m >>= 1) {
                mn = fminf(mn, __shfl_xor(mn, m));
                mx = fmaxf(mx, __shfl_xor(mx, m));
            }
            if (lane == 0) { mmp[strip * 2] = mn; mmp[strip * 2 + 1] = mx; }
        }
    } else {
        // ---- weight packing: w1 -> w1t4[c4*256+o], w2 -> w2t4[o4*128+c] ----
        int idx = (bid - 360) * 256 + tid;        // 256 blocks x 256 = 65536
        if (idx < 32768) {
            int o = idx >> 7, c = idx & 127;
            w1t[(size_t)((c >> 2) * 256 + o) * 4 + (c & 3)] = w1[idx];
        } else {
            int i2 = idx - 32768;
            int c = i2 >> 8, oo = i2 & 255;
            w2t[(size_t)((oo >> 2) * 128 + c) * 4 + (oo & 3)] = w2[i2];
        }
    }
}

// ===== kernel B: preamble (GN finalize + minmax reduce) + IPG + GN + FFN ==
__global__ __launch_bounds__(256, 4) void kB(const float* __restrict__ xt,
                                             const float* __restrict__ rn,
                                             const float* __restrict__ df,
                                             const float* __restrict__ mmp,
                                             const float* __restrict__ gnp,
                                             const float* __restrict__ gamma,
                                             const float* __restrict__ beta,
                                             const float* __restrict__ w1t,
                                             const float* __restrict__ w2t,
                                             const float* __restrict__ b1f,
                                             const float* __restrict__ b2f,
                                             float* __restrict__ out) {
    __shared__ union {
        float sims[4][176];                       // 2.8 KB
        struct { float elds[4][128]; float hlds[4][256]; } f;  // 6 KB
    } sm;
    __shared__ float gnbl[32][2];
    __shared__ float mml[2];
    const int tid = threadIdx.x, wv = tid >> 6, lane = tid & 63;
    const int base = blockIdx.x * 4;              // 1152 blocks, 4 px (4 | PP)
    const int b = base / PP;

    // preamble: per-block GN finalize + df min/max for this batch
    if (tid < 32) {
        const int g = tid, q = g >> 3, j = g & 7;
        float s = 0.f, sq = 0.f;
#pragma unroll 4
        for (int t2 = 0; t2 < 36; t2++) {
            int u = (b * 36 + t2) * 4 + q;
            s += gnp[u * 16 + j * 2];
            sq += gnp[u * 16 + j * 2 + 1];
        }
        float mu = s / 9216.f;
        float var = sq / 9216.f - mu * mu;
        gnbl[g][0] = mu;
        gnbl[g][1] = 1.f / sqrtf(var + 1e-5f);
    } else if (tid >= 64 && tid < 128) {
        int i = tid - 64;
        float mn = 1e30f, mx = -1e30f;
        if (i < 36) { mn = mmp[(b * 36 + i) * 2]; mx = mmp[(b * 36 + i) * 2 + 1]; }
#pragma unroll
        for (int m = 32; m; m >>= 1) {
            mn = fminf(mn, __shfl_xor(mn, m));
            mx = fmaxf(mx, __shfl_xor(mx, m));
        }
        if (i == 0) { mml[0] = mn; mml[1] = mx; }
    }
    __syncthreads();
    const float dmin = mml[0], dmax = mml[1];

    const int pix = base + wv;
    const int p = pix % PP;
    const int h = p / WW, w = p % WW;
    const int bb = b * PP;
    const int g8 = lane >> 3, cl = lane & 7;

    float4 ctr[4];
    const float4* cp = (const float4*)(xt + (size_t)pix * CH) + cl;
#pragma unroll
    for (int c = 0; c < 4; c++) ctr[c] = cp[c * 8];
    const float rnp = rn[pix];

    // sims: 22 batches x 8 offsets; group g8 = offset, cl = 4-ch slice
    for (int kb = 0; kb < 176; kb += 8) {
        const int k = kb + g8;
        const int krow = k / 13, kcol = k - krow * 13;
        const int yy = refl(h + krow - 6), xx = refl(w + kcol - 6);
        const int p2 = bb + yy * WW + xx;
        const float4* rp = (const float4*)(xt + (size_t)p2 * CH) + cl;
        float dot = 0.f;
#pragma unroll
        for (int c = 0; c < 4; c++) {
            float4 v = rp[c * 8];
            dot += v.x * ctr[c].x + v.y * ctr[c].y + v.z * ctr[c].z + v.w * ctr[c].w;
        }
        dot += __shfl_xor(dot, 1);
        dot += __shfl_xor(dot, 2);
        dot += __shfl_xor(dot, 4);
        float s = dot * rnp * rn[p2];
        if (cl == 0 && k < K2) sm.sims[wv][k] = s;
    }

    // top-cc extraction (value desc, index asc) + fused gather
    float s0 = sm.sims[wv][lane];
    float s1 = (64 + lane < K2) ? sm.sims[wv][64 + lane] : -1e30f;
    float s2 = (128 + lane < K2) ? sm.sims[wv][128 + lane] : -1e30f;
    const float dn = (df[pix] - dmin) / (dmax - dmin + 1e-8f);
    const int cc = 1 + (int)rintf(dn * 15.f);

    float wsum = 0.f, ax = 0.f, ay = 0.f;
    for (int i = 0; i < cc; ++i) {
        float gm = fmaxf(fmaxf(s0, s1), s2);
#pragma unroll
        for (int sft = 1; sft <= 32; sft <<= 1) gm = fmaxf(gm, __shfl_xor(gm, sft));
        unsigned long long m0 = __ballot(s0 == gm);
        unsigned long long m1 = __ballot(s1 == gm);
        unsigned long long m2 = __ballot(s2 == gm);
        int kw = m0 ? (__ffsll(m0) - 1)
               : m1 ? (64 + __ffsll(m1) - 1)
                    : (128 + __ffsll(m2) - 1);
        bool me = (lane == (kw & 63));
        s0 = (me && kw < 64) ? -1e30f : s0;
        s1 = (me && kw >= 64 && kw < 128) ? -1e30f : s1;
        s2 = (me && kw >= 128) ? -1e30f : s2;
        float wt = expf(gm);
        wsum += wt;
        int krow = kw / 13, kcol = kw - krow * 13;
        int p2 = bb + refl(h + krow - 6) * WW + refl(w + kcol - 6);
        float2 v = ((const float2*)(xt + (size_t)p2 * CH))[lane];
        ax += wt * v.x; ay += wt * v.y;
    }
    const float invw = 1.f / wsum;

    // GroupNorm + residual -> enhanced (registers)
    float2 xv = ((const float2*)(xt + (size_t)pix * CH))[lane];
    const int c0 = lane * 2, grp = lane >> 1;
    const float mu = gnbl[grp][0], rstd = gnbl[grp][1];
    float e0 = ax * invw + (xv.x - mu) * rstd * gamma[c0] + beta[c0];
    float e1 = ay * invw + (xv.y - mu) * rstd * gamma[c0 + 1] + beta[c0 + 1];

    __syncthreads();                              // all waves done with sims LDS
    ((float2*)sm.f.elds[wv])[lane] = make_float2(e0, e1);
    __syncthreads();

    // FFN stage 1: thread = output o; w1t4 coalesced, elds LDS broadcast
    {
        float acc4[4] = {0.f, 0.f, 0.f, 0.f};
        const float4* wp = ((const float4*)w1t) + tid;
        for (int c4 = 0; c4 < 32; c4++) {
            float4 wv4 = wp[c4 * 256];
#pragma unroll
            for (int px = 0; px < 4; px++) {
                float4 ev = *(const float4*)&sm.f.elds[px][c4 * 4];
                acc4[px] += wv4.x * ev.x + wv4.y * ev.y + wv4.z * ev.z + wv4.w * ev.w;
            }
        }
        float bv = b1f[tid];
#pragma unroll
        for (int px = 0; px < 4; px++)
            sm.f.hlds[px][tid] = fmaxf(acc4[px] + bv, 0.f);
    }
    __syncthreads();
    // FFN stage 2 + residual: thread = (c, hf); w2t4 coalesced
    {
        const int c = tid & 127, hf = tid >> 7;
        const int px0 = hf * 2;
        float acc2[2] = {0.f, 0.f};
        const float4* wp2 = ((const float4*)w2t) + c;
        for (int o4 = 0; o4 < 64; o4++) {
            float4 wv4 = wp2[o4 * 128];
#pragma unroll
            for (int j = 0; j < 2; j++) {
                float4 hv = *(const float4*)&sm.f.hlds[px0 + j][o4 * 4];
                acc2[j] += wv4.x * hv.x + wv4.y * hv.y + wv4.z * hv.z + wv4.w * hv.w;
            }
        }
        float bv = b2f[c];
        float2 o2;
        o2.x = sm.f.elds[px0 + 0][c] + acc2[0] + bv;
        o2.y = sm.f.elds[px0 + 1][c] + acc2[1] + bv;
        *(float2*)(out + ((size_t)(b * CH + c)) * PP + (base % PP) + px0) = o2;
    }
}

extern "C" void kernel_launch(void* const* d_in, const int* in_sizes, int n_in,
                              void* d_out, int out_size, void* d_ws, size_t ws_size,
                              hipStream_t stream) {
    (void)in_sizes; (void)n_in; (void)out_size;
    if (ws_size < WS_FLOATS * sizeof(float)) return;  // would corrupt; fail visibly

    const float* x     = (const float*)d_in[0];
    const float* gamma = (const float*)d_in[1];
    const float* beta  = (const float*)d_in[2];
    const float* w1    = (const float*)d_in[3];
    const float* b1    = (const float*)d_in[4];
    const float* w2    = (const float*)d_in[5];
    const float* b2    = (const float*)d_in[6];
    float* ws = (float*)d_ws;
    float* xt  = ws + OFF_XT;
    float* rn  = ws + OFF_RN;
    float* df  = ws + OFF_DF;
    float* gnp = ws + OFF_GNP;
    float* mmp = ws + OFF_MMP;
    float* w1t = ws + OFF_W1T;
    float* w2t = ws + OFF_W2T;
    float* out = (float*)d_out;

    hipLaunchKernelGGL(kA, dim3(616),  dim3(256), 0, stream,
                       x, w1, w2, xt, gnp, w1t, w2t, df, rn, mmp);
    hipLaunchKernelGGL(kB, dim3(1152), dim3(256), 0, stream,
                       xt, rn, df, mmp, gnp, gamma, beta, w1t, w2t, b1, b2, out);
}